// Round 1
// baseline (29088.681 us; speedup 1.0000x reference)
//
#include <hip/hip_runtime.h>

#define NG 50000
#define NR 12000
#define NSC 12      // 2*num_scales
#define EPS_N 50000
#define ELR_N 5000
#define E1_N 150000
#define E2_N 150000
#define GN_EPS_F 1e-5f

// ---------------------------------------------------------------------------
// mm128_k: out[row] = epilogue( in[gidx?[row]] @ W^T )
//   lane-per-row scheme: W (128x128) staged in LDS, read uniform (broadcast);
//   the lane's input row streams from global; the full output row (128 f32)
//   lives in this lane's registers, so GroupNorm is lane-local.
// EPI: 0 = raw store, 1 = relu(gn(x)), 3 = relu(gn(x) + add)
// SCATTER: atomicAdd the raw row into out[sidx[row]] (EPI ignored)
// ---------------------------------------------------------------------------
template<int EPI, bool GATHER, bool SCATTER>
__launch_bounds__(256)
__global__ void mm128_k(const float* __restrict__ in,
                        const float* __restrict__ W, int wstride,
                        const float* __restrict__ sb,
                        const float* __restrict__ addsrc,
                        float* __restrict__ out,
                        const int* __restrict__ gidx,
                        const int* __restrict__ sidx,
                        int nrows)
{
    __shared__ float wS[128 * 128];
    const int tid = threadIdx.x;
    #pragma unroll 1
    for (int idx = tid; idx < 128 * 128; idx += 256) {
        int j = idx >> 7, k = idx & 127;
        wS[idx] = W[j * wstride + k];
    }
    __syncthreads();

    const int row = blockIdx.x * 256 + tid;
    if (row >= nrows) return;
    const int srow = GATHER ? gidx[row] : row;
    const float* __restrict__ x = in + (size_t)srow * 128;

    float acc[128];
    #pragma unroll
    for (int j = 0; j < 128; ++j) acc[j] = 0.f;

    #pragma unroll 1
    for (int k4 = 0; k4 < 32; ++k4) {
        const float4 xv = *reinterpret_cast<const float4*>(x + k4 * 4);
        #pragma unroll
        for (int j = 0; j < 128; ++j) {
            const float4 wv = *reinterpret_cast<const float4*>(&wS[j * 128 + k4 * 4]);
            acc[j] = fmaf(xv.x, wv.x, acc[j]);
            acc[j] = fmaf(xv.y, wv.y, acc[j]);
            acc[j] = fmaf(xv.z, wv.z, acc[j]);
            acc[j] = fmaf(xv.w, wv.w, acc[j]);
        }
    }

    if (SCATTER) {
        float* dst = out + (size_t)sidx[row] * 128;
        #pragma unroll
        for (int j = 0; j < 128; ++j) atomicAdd(dst + j, acc[j]);
        return;
    }

    float* dst = out + (size_t)row * 128;
    if (EPI == 0) {
        #pragma unroll
        for (int j4 = 0; j4 < 32; ++j4) {
            float4 v = make_float4(acc[j4*4+0], acc[j4*4+1], acc[j4*4+2], acc[j4*4+3]);
            *reinterpret_cast<float4*>(dst + j4 * 4) = v;
        }
        return;
    }

    // GroupNorm(num_groups=1) over the 128 values held in-lane (two-pass).
    float s = 0.f;
    #pragma unroll
    for (int j = 0; j < 128; ++j) s += acc[j];
    const float m = s * (1.f / 128.f);
    float s2 = 0.f;
    #pragma unroll
    for (int j = 0; j < 128; ++j) { float d = acc[j] - m; s2 = fmaf(d, d, s2); }
    const float inv = rsqrtf(s2 * (1.f / 128.f) + GN_EPS_F);

    const float* __restrict__ ap = (EPI == 3) ? (addsrc + (size_t)row * 128) : nullptr;
    #pragma unroll
    for (int j4 = 0; j4 < 32; ++j4) {
        float4 o;
        #pragma unroll
        for (int q = 0; q < 4; ++q) {
            const int j = j4 * 4 + q;
            float t = (acc[j] - m) * inv * sb[j] + sb[128 + j];
            if (EPI == 3) t += ap[j];
            (&o.x)[q] = fmaxf(t, 0.f);
        }
        *reinterpret_cast<float4*>(dst + j4 * 4) = o;
    }
}

// ---------------------------------------------------------------------------
// edge_stage1_k: for each edge e (lane-per-edge):
//   dist_k = relu((ctx_pose[hi]-tgt_pose[wi]) . rpw[k] + rpb[k])   (on the fly)
//   acc    = prectx[hi] + dist @ ctx1_w[:,128:].T
//   rbuf[e-ebase] = relu(gn(acc, ctx1_gn))
// ctx1_wB is staged transposed in LDS: wT[k*128+j] so the j-sweep is a uniform
// contiguous b128 broadcast per k.
// ---------------------------------------------------------------------------
__launch_bounds__(256)
__global__ void edge_stage1_k(const int* __restrict__ hi_idx,
                              const int* __restrict__ wi_idx,
                              int ebase, int ecount,
                              const float* __restrict__ ctx_pose,
                              const float* __restrict__ tgt_pose,
                              const float* __restrict__ rpw,   // [128][4]
                              const float* __restrict__ rpb,   // [128]
                              const float* __restrict__ c1w,   // [128][256], B part at col 128
                              const float* __restrict__ sb,    // ctx1_gn [2][128]
                              const float* __restrict__ prectx,
                              float* __restrict__ rbuf)
{
    __shared__ float wT[128 * 128];  // wT[k*128+j] = c1w[j*256 + 128 + k]
    const int tid = threadIdx.x;
    #pragma unroll 1
    for (int idx = tid; idx < 128 * 128; idx += 256) {
        int j = idx & 127, k = idx >> 7;
        wT[idx] = c1w[j * 256 + 128 + k];
    }
    __syncthreads();

    const int r = blockIdx.x * 256 + tid;
    if (r >= ecount) return;
    const int e = ebase + r;
    const int hi = hi_idx[e];
    const int wi = wi_idx[e];
    const float4 cp = *reinterpret_cast<const float4*>(ctx_pose + (size_t)hi * 4);
    const float4 tp = *reinterpret_cast<const float4*>(tgt_pose + (size_t)wi * 4);
    const float d0 = cp.x - tp.x, d1 = cp.y - tp.y, d2 = cp.z - tp.z, d3 = cp.w - tp.w;

    float acc[128];
    const float* __restrict__ pc = prectx + (size_t)hi * 128;
    #pragma unroll
    for (int j4 = 0; j4 < 32; ++j4) {
        float4 p = *reinterpret_cast<const float4*>(pc + j4 * 4);
        acc[j4*4+0] = p.x; acc[j4*4+1] = p.y; acc[j4*4+2] = p.z; acc[j4*4+3] = p.w;
    }

    #pragma unroll 1
    for (int k = 0; k < 128; ++k) {
        const float4 rw = *reinterpret_cast<const float4*>(rpw + k * 4);
        float dk = fmaf(d0, rw.x, fmaf(d1, rw.y, fmaf(d2, rw.z, fmaf(d3, rw.w, rpb[k]))));
        dk = fmaxf(dk, 0.f);
        const float* __restrict__ wr = &wT[k * 128];
        #pragma unroll
        for (int j4 = 0; j4 < 32; ++j4) {
            const float4 wv = *reinterpret_cast<const float4*>(wr + j4 * 4);
            acc[j4*4+0] = fmaf(dk, wv.x, acc[j4*4+0]);
            acc[j4*4+1] = fmaf(dk, wv.y, acc[j4*4+1]);
            acc[j4*4+2] = fmaf(dk, wv.z, acc[j4*4+2]);
            acc[j4*4+3] = fmaf(dk, wv.w, acc[j4*4+3]);
        }
    }

    // gn + relu (lane-local)
    float s = 0.f;
    #pragma unroll
    for (int j = 0; j < 128; ++j) s += acc[j];
    const float m = s * (1.f / 128.f);
    float s2 = 0.f;
    #pragma unroll
    for (int j = 0; j < 128; ++j) { float d = acc[j] - m; s2 = fmaf(d, d, s2); }
    const float inv = rsqrtf(s2 * (1.f / 128.f) + GN_EPS_F);

    float* __restrict__ dst = rbuf + (size_t)r * 128;
    #pragma unroll
    for (int j4 = 0; j4 < 32; ++j4) {
        float4 o;
        #pragma unroll
        for (int q = 0; q < 4; ++q) {
            const int j = j4 * 4 + q;
            (&o.x)[q] = fmaxf((acc[j] - m) * inv * sb[j] + sb[128 + j], 0.f);
        }
        *reinterpret_cast<float4*>(dst + j4 * 4) = o;
    }
}

// ---------------------------------------------------------------------------
// rowgn_k: out[row] = relu(gn(in[row], sb))   (lane-per-row)
// ---------------------------------------------------------------------------
__launch_bounds__(256)
__global__ void rowgn_k(const float* __restrict__ in, const float* __restrict__ sb,
                        float* __restrict__ out, int nrows)
{
    const int row = blockIdx.x * 256 + threadIdx.x;
    if (row >= nrows) return;
    const float* __restrict__ x = in + (size_t)row * 128;
    float v[128];
    #pragma unroll
    for (int j4 = 0; j4 < 32; ++j4) {
        float4 p = *reinterpret_cast<const float4*>(x + j4 * 4);
        v[j4*4+0] = p.x; v[j4*4+1] = p.y; v[j4*4+2] = p.z; v[j4*4+3] = p.w;
    }
    float s = 0.f;
    #pragma unroll
    for (int j = 0; j < 128; ++j) s += v[j];
    const float m = s * (1.f / 128.f);
    float s2 = 0.f;
    #pragma unroll
    for (int j = 0; j < 128; ++j) { float d = v[j] - m; s2 = fmaf(d, d, s2); }
    const float inv = rsqrtf(s2 * (1.f / 128.f) + GN_EPS_F);
    float* __restrict__ dst = out + (size_t)row * 128;
    #pragma unroll
    for (int j4 = 0; j4 < 32; ++j4) {
        float4 o;
        #pragma unroll
        for (int q = 0; q < 4; ++q) {
            const int j = j4 * 4 + q;
            (&o.x)[q] = fmaxf((v[j] - m) * inv * sb[j] + sb[128 + j], 0.f);
        }
        *reinterpret_cast<float4*>(dst + j4 * 4) = o;
    }
}

// ---------------------------------------------------------------------------
extern "C" void kernel_launch(void* const* d_in, const int* in_sizes, int n_in,
                              void* d_out, int out_size, void* d_ws, size_t ws_size,
                              hipStream_t stream)
{
    const float* roi_feat   = (const float*)d_in[0];
    const float* graph_pose = (const float*)d_in[1];
    const float* roi_pose   = (const float*)d_in[2];
    const float* lp_input_w = (const float*)d_in[3];
    const float* lp_rpw     = (const float*)d_in[4];
    const float* lp_rpb     = (const float*)d_in[5];
    const float* lp_c1w     = (const float*)d_in[6];
    const float* lp_c1gn    = (const float*)d_in[7];
    const float* lp_c2w     = (const float*)d_in[8];
    const float* lp_m1w     = (const float*)d_in[9];
    const float* lp_m1gn    = (const float*)d_in[10];
    const float* lp_m2w     = (const float*)d_in[11];
    const float* lp_m2gn    = (const float*)d_in[12];
    const float* lp_ngn     = (const float*)d_in[13];
    const float* f_ctrw     = (const float*)d_in[14];
    const float* f_psw      = (const float*)d_in[15];
    const float* f_lw       = (const float*)d_in[16];
    const float* f_rw       = (const float*)d_in[17];
    const float* f_ngn      = (const float*)d_in[18];
    const float* f_c2w      = (const float*)d_in[19];
    const float* f_c2gn     = (const float*)d_in[20];
    const int* e1_hi = (const int*)d_in[21];
    const int* e1_wi = (const int*)d_in[22];
    const int* e2_hi = (const int*)d_in[23];
    const int* e2_wi = (const int*)d_in[24];
    const int* ps_u  = (const int*)d_in[25];
    const int* ps_v  = (const int*)d_in[26];
    const int* lr_u  = (const int*)d_in[27];
    const int* lr_v  = (const int*)d_in[28];
    float* out = (float*)d_out;

    // workspace layout (floats): 3*NG*128 + 3*NR*128 + 50000*128  (~119 MB)
    float* ws    = (float*)d_ws;
    float* gfeat = ws;
    float* tmpG  = gfeat + (size_t)NG * 128;
    float* midG  = tmpG  + (size_t)NG * 128;
    float* pre1  = midG  + (size_t)NG * 128;
    float* tR    = pre1  + (size_t)NR * 128;
    float* tR2   = tR    + (size_t)NR * 128;
    float* rbuf  = tR2   + (size_t)NR * 128;
    const int CH = 50000;

    dim3 blk(256);
    auto grd = [](int n) { return dim3((unsigned)((n + 255) / 256)); };

    // ------------- lane_pooling #1 (roi -> graph), tgt_feat = 0 -------------
    // prectx1 = roi_feat @ ctx1_w[0][:, :128].T
    mm128_k<0,false,false><<<grd(NR), blk, 0, stream>>>(
        roi_feat, lp_c1w, 256, nullptr, nullptr, pre1, nullptr, nullptr, NR);
    hipMemsetAsync(tmpG, 0, (size_t)NG * 128 * sizeof(float), stream);
    for (int c = 0; c < E1_N; c += CH) {
        int rem = E1_N - c; int ec = rem < CH ? rem : CH;
        edge_stage1_k<<<grd(ec), blk, 0, stream>>>(
            e1_hi, e1_wi, c, ec, roi_pose, graph_pose,
            lp_rpw, lp_rpb, lp_c1w, lp_c1gn, pre1, rbuf);
        mm128_k<0,false,true><<<grd(ec), blk, 0, stream>>>(
            rbuf, lp_c2w, 128, nullptr, nullptr, tmpG, nullptr, e1_wi + c, ec);
    }
    rowgn_k<<<grd(NG), blk, 0, stream>>>(tmpG, lp_ngn, midG, NG);
    mm128_k<1,false,false><<<grd(NG), blk, 0, stream>>>(
        midG, lp_m1w, 128, lp_m1gn, nullptr, tmpG, nullptr, nullptr, NG);
    mm128_k<1,false,false><<<grd(NG), blk, 0, stream>>>(
        tmpG, lp_m2w, 128, lp_m2gn, nullptr, gfeat, nullptr, nullptr, NG);

    // ----------------------------- global_graph -----------------------------
    for (int i = 0; i < 4; ++i) {
        mm128_k<0,false,false><<<grd(NG), blk, 0, stream>>>(
            gfeat, f_ctrw + (size_t)i * 16384, 128, nullptr, nullptr, tmpG,
            nullptr, nullptr, NG);
        for (int k = 0; k < NSC; ++k) {
            mm128_k<0,true,true><<<grd(EPS_N), blk, 0, stream>>>(
                gfeat, f_psw + ((size_t)i * NSC + k) * 16384, 128,
                nullptr, nullptr, tmpG,
                ps_v + (size_t)k * EPS_N, ps_u + (size_t)k * EPS_N, EPS_N);
        }
        mm128_k<0,true,true><<<grd(ELR_N), blk, 0, stream>>>(
            gfeat, f_lw + (size_t)i * 16384, 128, nullptr, nullptr, tmpG,
            lr_v, lr_u, ELR_N);
        mm128_k<0,true,true><<<grd(ELR_N), blk, 0, stream>>>(
            gfeat, f_rw + (size_t)i * 16384, 128, nullptr, nullptr, tmpG,
            lr_v + ELR_N, lr_u + ELR_N, ELR_N);
        rowgn_k<<<grd(NG), blk, 0, stream>>>(tmpG, f_ngn + (size_t)i * 256, midG, NG);
        // gfeat = relu(gn(midG @ ctr2.T) + gfeat)   (res == layer input)
        mm128_k<3,false,false><<<grd(NG), blk, 0, stream>>>(
            midG, f_c2w + (size_t)i * 16384, 128, f_c2gn + (size_t)i * 256,
            gfeat, gfeat, nullptr, nullptr, NG);
    }

    // ------------- lane_pooling #2 (graph -> roi), identity = roi_feat ------
    // prectx2 = gfeat @ ctx1_w[1][:, :128].T  -> midG
    mm128_k<0,false,false><<<grd(NG), blk, 0, stream>>>(
        gfeat, lp_c1w + 32768, 256, nullptr, nullptr, midG, nullptr, nullptr, NG);
    // tR = roi_feat @ input_w[1].T
    mm128_k<0,false,false><<<grd(NR), blk, 0, stream>>>(
        roi_feat, lp_input_w + 16384, 128, nullptr, nullptr, tR, nullptr, nullptr, NR);
    for (int c = 0; c < E2_N; c += CH) {
        int rem = E2_N - c; int ec = rem < CH ? rem : CH;
        edge_stage1_k<<<grd(ec), blk, 0, stream>>>(
            e2_hi, e2_wi, c, ec, graph_pose, roi_pose,
            lp_rpw + 512, lp_rpb + 128, lp_c1w + 32768, lp_c1gn + 256, midG, rbuf);
        mm128_k<0,false,true><<<grd(ec), blk, 0, stream>>>(
            rbuf, lp_c2w + 16384, 128, nullptr, nullptr, tR, nullptr, e2_wi + c, ec);
    }
    rowgn_k<<<grd(NR), blk, 0, stream>>>(tR, lp_ngn + 256, tR2, NR);
    mm128_k<1,false,false><<<grd(NR), blk, 0, stream>>>(
        tR2, lp_m1w + 16384, 128, lp_m1gn + 256, nullptr, tR, nullptr, nullptr, NR);
    mm128_k<3,false,false><<<grd(NR), blk, 0, stream>>>(
        tR, lp_m2w + 16384, 128, lp_m2gn + 256, roi_feat, out, nullptr, nullptr, NR);
}

// Round 2
// 2098.693 us; speedup vs baseline: 13.8604x; 13.8604x over previous
//
#include <hip/hip_runtime.h>

#define NG 50000
#define NR 12000
#define EPS_N 50000
#define ELR_N 5000
#define E1_N 150000
#define E2_N 150000
#define GN_EPS_F 1e-5f

typedef __attribute__((ext_vector_type(8))) __bf16 bf16x8;
typedef __attribute__((ext_vector_type(4))) float f32x4;

__device__ __forceinline__ bf16x8 cvt8(const float* __restrict__ p) {
    float4 x0 = *reinterpret_cast<const float4*>(p);
    float4 x1 = *reinterpret_cast<const float4*>(p + 4);
    bf16x8 a;
    a[0] = (__bf16)x0.x; a[1] = (__bf16)x0.y; a[2] = (__bf16)x0.z; a[3] = (__bf16)x0.w;
    a[4] = (__bf16)x1.x; a[5] = (__bf16)x1.y; a[6] = (__bf16)x1.z; a[7] = (__bf16)x1.w;
    return a;
}

// ---------------------------------------------------------------------------
// gemm128_k: C[M,128] = A[gidx?,:128] @ W[128,128]^T   (bf16 MFMA, fp32 accum)
//   block: 256 thr = 4 waves in 2(M)x2(N); BM=64, BN=128, K=128 fixed.
//   A-frag = X[row][k:k+8] contiguous; B-frag = W[col][k:k+8] contiguous.
//   grid.y = z batches W (stride wzs) and index arrays (stride izs).
//   SCATTER: atomicAdd rows into Cout[sidx[row]].
// ---------------------------------------------------------------------------
template<bool GATHER, bool SCATTER>
__launch_bounds__(256)
__global__ void gemm128_k(const float* __restrict__ A,
                          const float* __restrict__ Wb, int wrs, int wzs,
                          float* __restrict__ Cout,
                          const int* __restrict__ gidx,
                          const int* __restrict__ sidx,
                          int izs, int M)
{
    const int tid = threadIdx.x;
    const int lane = tid & 63;
    const int wave = tid >> 6;
    const int waveM = wave >> 1, waveN = wave & 1;
    const int r16 = lane & 15, kq = lane >> 4;
    const int mbase = blockIdx.x * 64 + waveM * 32;
    const int z = blockIdx.y;
    const float* __restrict__ W = Wb + (size_t)z * wzs;
    const int* __restrict__ gi = GATHER ? (gidx + (size_t)z * izs) : nullptr;
    const int* __restrict__ si = SCATTER ? (sidx + (size_t)z * izs) : nullptr;

    bf16x8 b[4][4];
    #pragma unroll
    for (int ni = 0; ni < 4; ++ni) {
        const int col = waveN * 64 + ni * 16 + r16;
        #pragma unroll
        for (int ks = 0; ks < 4; ++ks)
            b[ni][ks] = cvt8(W + (size_t)col * wrs + ks * 32 + kq * 8);
    }

    int asrc[2];
    #pragma unroll
    for (int mi = 0; mi < 2; ++mi) {
        int r = mbase + mi * 16 + r16;
        int rc = r < M ? r : M - 1;
        asrc[mi] = GATHER ? gi[rc] : rc;
    }

    f32x4 acc[2][4];
    #pragma unroll
    for (int mi = 0; mi < 2; ++mi)
        #pragma unroll
        for (int ni = 0; ni < 4; ++ni)
            acc[mi][ni] = (f32x4){0.f, 0.f, 0.f, 0.f};

    #pragma unroll
    for (int ks = 0; ks < 4; ++ks) {
        bf16x8 a[2];
        #pragma unroll
        for (int mi = 0; mi < 2; ++mi)
            a[mi] = cvt8(A + (size_t)asrc[mi] * 128 + ks * 32 + kq * 8);
        #pragma unroll
        for (int mi = 0; mi < 2; ++mi)
            #pragma unroll
            for (int ni = 0; ni < 4; ++ni)
                acc[mi][ni] = __builtin_amdgcn_mfma_f32_16x16x32_bf16(
                    a[mi], b[ni][ks], acc[mi][ni], 0, 0, 0);
    }

    #pragma unroll
    for (int mi = 0; mi < 2; ++mi) {
        const int rb = mbase + mi * 16 + kq * 4;
        #pragma unroll
        for (int reg = 0; reg < 4; ++reg) {
            const int crow = rb + reg;
            if (crow >= M) continue;
            const int orow = SCATTER ? si[crow] : crow;
            float* dst = Cout + (size_t)orow * 128 + waveN * 64 + r16;
            #pragma unroll
            for (int ni = 0; ni < 4; ++ni) {
                if (SCATTER) atomicAdd(dst + ni * 16, acc[mi][ni][reg]);
                else dst[ni * 16] = acc[mi][ni][reg];
            }
        }
    }
}

// ---------------------------------------------------------------------------
// gemmdist_k: hbuf[e,:] = dist(e,:) @ c1B^T, dist built on the fly from poses:
//   dist_k = relu((cpose[hi[e]] - tpose[wi[e]]) . rpw[k] + rpb[k])
// Same wave/frag geometry as gemm128_k; rpw/rpb staged in LDS.
// ---------------------------------------------------------------------------
__launch_bounds__(256)
__global__ void gemmdist_k(const int* __restrict__ hi_idx, const int* __restrict__ wi_idx,
                           const float* __restrict__ cpose, const float* __restrict__ tpose,
                           const float* __restrict__ rpw, const float* __restrict__ rpb,
                           const float* __restrict__ Wb, int wrs,
                           float* __restrict__ Cout, int M)
{
    __shared__ float rw[128 * 4 + 128];
    const int tid = threadIdx.x;
    for (int i = tid; i < 640; i += 256)
        rw[i] = (i < 512) ? rpw[i] : rpb[i - 512];
    __syncthreads();

    const int lane = tid & 63;
    const int wave = tid >> 6;
    const int waveM = wave >> 1, waveN = wave & 1;
    const int r16 = lane & 15, kq = lane >> 4;
    const int mbase = blockIdx.x * 64 + waveM * 32;

    bf16x8 b[4][4];
    #pragma unroll
    for (int ni = 0; ni < 4; ++ni) {
        const int col = waveN * 64 + ni * 16 + r16;
        #pragma unroll
        for (int ks = 0; ks < 4; ++ks)
            b[ni][ks] = cvt8(Wb + (size_t)col * wrs + ks * 32 + kq * 8);
    }

    float dl[2][4];
    #pragma unroll
    for (int mi = 0; mi < 2; ++mi) {
        int r = mbase + mi * 16 + r16;
        int e = r < M ? r : M - 1;
        int hi = hi_idx[e], wi = wi_idx[e];
        float4 cp = *reinterpret_cast<const float4*>(cpose + (size_t)hi * 4);
        float4 tp = *reinterpret_cast<const float4*>(tpose + (size_t)wi * 4);
        dl[mi][0] = cp.x - tp.x; dl[mi][1] = cp.y - tp.y;
        dl[mi][2] = cp.z - tp.z; dl[mi][3] = cp.w - tp.w;
    }

    f32x4 acc[2][4];
    #pragma unroll
    for (int mi = 0; mi < 2; ++mi)
        #pragma unroll
        for (int ni = 0; ni < 4; ++ni)
            acc[mi][ni] = (f32x4){0.f, 0.f, 0.f, 0.f};

    #pragma unroll
    for (int ks = 0; ks < 4; ++ks) {
        bf16x8 a[2];
        #pragma unroll
        for (int mi = 0; mi < 2; ++mi) {
            #pragma unroll
            for (int i = 0; i < 8; ++i) {
                const int k = ks * 32 + kq * 8 + i;
                float4 w4 = *reinterpret_cast<const float4*>(&rw[k * 4]);
                float d = fmaf(dl[mi][0], w4.x, fmaf(dl[mi][1], w4.y,
                          fmaf(dl[mi][2], w4.z, fmaf(dl[mi][3], w4.w, rw[512 + k]))));
                a[mi][i] = (__bf16)fmaxf(d, 0.f);
            }
        }
        #pragma unroll
        for (int mi = 0; mi < 2; ++mi)
            #pragma unroll
            for (int ni = 0; ni < 4; ++ni)
                acc[mi][ni] = __builtin_amdgcn_mfma_f32_16x16x32_bf16(
                    a[mi], b[ni][ks], acc[mi][ni], 0, 0, 0);
    }

    #pragma unroll
    for (int mi = 0; mi < 2; ++mi) {
        const int rb = mbase + mi * 16 + kq * 4;
        #pragma unroll
        for (int reg = 0; reg < 4; ++reg) {
            const int crow = rb + reg;
            if (crow >= M) continue;
            float* dst = Cout + (size_t)crow * 128 + waveN * 64 + r16;
            #pragma unroll
            for (int ni = 0; ni < 4; ++ni)
                dst[ni * 16] = acc[mi][ni][reg];
        }
    }
}

// ---------------------------------------------------------------------------
// rowop_k: GroupNorm(1 group) + relu variants, 4 lanes per row (32 VGPR).
//   MODE 0: out = relu(gn(x))
//   MODE 1: out = relu(gn(x + pre[gidx[row]]))      (pre-GN gathered add)
//   MODE 2: out = relu(gn(x) + add[row])            (post-GN residual add)
// ---------------------------------------------------------------------------
template<int MODE>
__launch_bounds__(256)
__global__ void rowop_k(const float* __restrict__ in,
                        const float* __restrict__ sb,
                        const float* __restrict__ addp,
                        const int* __restrict__ gidx,
                        float* __restrict__ outp, int M)
{
    const int t = threadIdx.x;
    const int row = blockIdx.x * 64 + (t >> 2);
    if (row >= M) return;
    const int q = t & 3;
    const float* __restrict__ x = in + (size_t)row * 128 + q * 32;
    float v[32];
    #pragma unroll
    for (int i = 0; i < 8; ++i) {
        float4 p = *reinterpret_cast<const float4*>(x + i * 4);
        v[i*4+0] = p.x; v[i*4+1] = p.y; v[i*4+2] = p.z; v[i*4+3] = p.w;
    }
    if (MODE == 1) {
        const float* __restrict__ pp = addp + (size_t)gidx[row] * 128 + q * 32;
        #pragma unroll
        for (int i = 0; i < 8; ++i) {
            float4 p = *reinterpret_cast<const float4*>(pp + i * 4);
            v[i*4+0] += p.x; v[i*4+1] += p.y; v[i*4+2] += p.z; v[i*4+3] += p.w;
        }
    }
    float s = 0.f;
    #pragma unroll
    for (int i = 0; i < 32; ++i) s += v[i];
    s += __shfl_xor(s, 1); s += __shfl_xor(s, 2);
    const float m = s * (1.f / 128.f);
    float s2 = 0.f;
    #pragma unroll
    for (int i = 0; i < 32; ++i) { float d = v[i] - m; s2 = fmaf(d, d, s2); }
    s2 += __shfl_xor(s2, 1); s2 += __shfl_xor(s2, 2);
    const float inv = rsqrtf(s2 * (1.f / 128.f) + GN_EPS_F);

    float* __restrict__ dst = outp + (size_t)row * 128 + q * 32;
    const float* __restrict__ ad = (MODE == 2) ? addp + (size_t)row * 128 + q * 32 : nullptr;
    #pragma unroll
    for (int i = 0; i < 8; ++i) {
        float4 o;
        #pragma unroll
        for (int jj = 0; jj < 4; ++jj) {
            const int c = q * 32 + i * 4 + jj;
            float y = (v[i*4+jj] - m) * inv * sb[c] + sb[128 + c];
            if (MODE == 2) y += ad[i*4+jj];
            (&o.x)[jj] = fmaxf(y, 0.f);
        }
        *reinterpret_cast<float4*>(dst + i * 4) = o;
    }
}

// ---------------------------------------------------------------------------
extern "C" void kernel_launch(void* const* d_in, const int* in_sizes, int n_in,
                              void* d_out, int out_size, void* d_ws, size_t ws_size,
                              hipStream_t stream)
{
    const float* roi_feat   = (const float*)d_in[0];
    const float* graph_pose = (const float*)d_in[1];
    const float* roi_pose   = (const float*)d_in[2];
    const float* lp_input_w = (const float*)d_in[3];
    const float* lp_rpw     = (const float*)d_in[4];
    const float* lp_rpb     = (const float*)d_in[5];
    const float* lp_c1w     = (const float*)d_in[6];
    const float* lp_c1gn    = (const float*)d_in[7];
    const float* lp_c2w     = (const float*)d_in[8];
    const float* lp_m1w     = (const float*)d_in[9];
    const float* lp_m1gn    = (const float*)d_in[10];
    const float* lp_m2w     = (const float*)d_in[11];
    const float* lp_m2gn    = (const float*)d_in[12];
    const float* lp_ngn     = (const float*)d_in[13];
    const float* f_ctrw     = (const float*)d_in[14];
    const float* f_psw      = (const float*)d_in[15];
    const float* f_lw       = (const float*)d_in[16];
    const float* f_rw       = (const float*)d_in[17];
    const float* f_ngn      = (const float*)d_in[18];
    const float* f_c2w      = (const float*)d_in[19];
    const float* f_c2gn     = (const float*)d_in[20];
    const int* e1_hi = (const int*)d_in[21];
    const int* e1_wi = (const int*)d_in[22];
    const int* e2_hi = (const int*)d_in[23];
    const int* e2_wi = (const int*)d_in[24];
    const int* ps_u  = (const int*)d_in[25];
    const int* ps_v  = (const int*)d_in[26];
    const int* lr_u  = (const int*)d_in[27];
    const int* lr_v  = (const int*)d_in[28];
    float* out = (float*)d_out;

    // ws (floats): gfeat/tmpG/midG [NG*128] + hbuf [E1_N*128] + preN [NR*128] ≈ 160 MB
    float* gfeat = (float*)d_ws;
    float* tmpG  = gfeat + (size_t)NG * 128;
    float* midG  = tmpG  + (size_t)NG * 128;
    float* hbuf  = midG  + (size_t)NG * 128;
    float* preN  = hbuf  + (size_t)E1_N * 128;

    dim3 blk(256);
    const dim3 gNR((NR + 63) / 64), gNG((NG + 63) / 64), gE((E1_N + 63) / 64),
               gLR((ELR_N + 63) / 64);
    const dim3 gPS((EPS_N + 63) / 64, 12);

    // ------------- lane_pooling #1 (roi -> graph), tgt_feat = 0 -------------
    gemm128_k<false,false><<<gNR, blk, 0, stream>>>(
        roi_feat, lp_c1w, 256, 0, preN, nullptr, nullptr, 0, NR);
    hipMemsetAsync(tmpG, 0, (size_t)NG * 128 * sizeof(float), stream);
    gemmdist_k<<<gE, blk, 0, stream>>>(
        e1_hi, e1_wi, roi_pose, graph_pose, lp_rpw, lp_rpb,
        lp_c1w + 128, 256, hbuf, E1_N);
    rowop_k<1><<<gE, blk, 0, stream>>>(hbuf, lp_c1gn, preN, e1_hi, hbuf, E1_N);
    gemm128_k<false,true><<<gE, blk, 0, stream>>>(
        hbuf, lp_c2w, 128, 0, tmpG, nullptr, e1_wi, 0, E1_N);
    rowop_k<0><<<gNG, blk, 0, stream>>>(tmpG, lp_ngn, nullptr, nullptr, midG, NG);
    gemm128_k<false,false><<<gNG, blk, 0, stream>>>(
        midG, lp_m1w, 128, 0, tmpG, nullptr, nullptr, 0, NG);
    rowop_k<0><<<gNG, blk, 0, stream>>>(tmpG, lp_m1gn, nullptr, nullptr, midG, NG);
    gemm128_k<false,false><<<gNG, blk, 0, stream>>>(
        midG, lp_m2w, 128, 0, tmpG, nullptr, nullptr, 0, NG);
    rowop_k<0><<<gNG, blk, 0, stream>>>(tmpG, lp_m2gn, nullptr, nullptr, gfeat, NG);

    // ----------------------------- global_graph -----------------------------
    for (int i = 0; i < 4; ++i) {
        gemm128_k<false,false><<<gNG, blk, 0, stream>>>(
            gfeat, f_ctrw + (size_t)i * 16384, 128, 0, tmpG, nullptr, nullptr, 0, NG);
        gemm128_k<true,true><<<gPS, blk, 0, stream>>>(
            gfeat, f_psw + (size_t)i * 12 * 16384, 128, 16384, tmpG,
            ps_v, ps_u, EPS_N, EPS_N);
        gemm128_k<true,true><<<gLR, blk, 0, stream>>>(
            gfeat, f_lw + (size_t)i * 16384, 128, 0, tmpG, lr_v, lr_u, 0, ELR_N);
        gemm128_k<true,true><<<gLR, blk, 0, stream>>>(
            gfeat, f_rw + (size_t)i * 16384, 128, 0, tmpG,
            lr_v + ELR_N, lr_u + ELR_N, 0, ELR_N);
        rowop_k<0><<<gNG, blk, 0, stream>>>(
            tmpG, f_ngn + (size_t)i * 256, nullptr, nullptr, midG, NG);
        gemm128_k<false,false><<<gNG, blk, 0, stream>>>(
            midG, f_c2w + (size_t)i * 16384, 128, 0, hbuf, nullptr, nullptr, 0, NG);
        rowop_k<2><<<gNG, blk, 0, stream>>>(
            hbuf, f_c2gn + (size_t)i * 256, gfeat, nullptr, gfeat, NG);
    }

    // ------------- lane_pooling #2 (graph -> roi), identity = roi_feat ------
    gemm128_k<false,false><<<gNG, blk, 0, stream>>>(
        gfeat, lp_c1w + 32768, 256, 0, tmpG, nullptr, nullptr, 0, NG);   // prectxG
    gemm128_k<false,false><<<gNR, blk, 0, stream>>>(
        roi_feat, lp_input_w + 16384, 128, 0, preN, nullptr, nullptr, 0, NR); // tR
    gemmdist_k<<<gE, blk, 0, stream>>>(
        e2_hi, e2_wi, graph_pose, roi_pose, lp_rpw + 512, lp_rpb + 128,
        lp_c1w + 32768 + 128, 256, hbuf, E2_N);
    rowop_k<1><<<gE, blk, 0, stream>>>(hbuf, lp_c1gn + 256, tmpG, e2_hi, hbuf, E2_N);
    gemm128_k<false,true><<<gE, blk, 0, stream>>>(
        hbuf, lp_c2w + 16384, 128, 0, preN, nullptr, e2_wi, 0, E2_N);
    rowop_k<0><<<gNR, blk, 0, stream>>>(preN, lp_ngn + 256, nullptr, nullptr, midG, NR);
    gemm128_k<false,false><<<gNR, blk, 0, stream>>>(
        midG, lp_m1w + 16384, 128, 0, tmpG, nullptr, nullptr, 0, NR);
    rowop_k<0><<<gNR, blk, 0, stream>>>(tmpG, lp_m1gn + 256, nullptr, nullptr, midG, NR);
    gemm128_k<false,false><<<gNR, blk, 0, stream>>>(
        midG, lp_m2w + 16384, 128, 0, tmpG, nullptr, nullptr, 0, NR);
    rowop_k<2><<<gNR, blk, 0, stream>>>(
        tmpG, lp_m2gn + 256, roi_feat, nullptr, out, NR);
}